// Round 9
// baseline (627.022 us; speedup 1.0000x reference)
//
#include <hip/hip_runtime.h>
#include <math.h>

#define LPOS 4096   // H*W
#define NB 16       // batch

typedef __bf16 bf16;
typedef __bf16 bf16x8 __attribute__((ext_vector_type(8)));
typedef __bf16 bf16x4 __attribute__((ext_vector_type(4)));
typedef float f32x4 __attribute__((ext_vector_type(4)));

#define GLOAD_LDS16(g, l) \
    __builtin_amdgcn_global_load_lds((const __attribute__((address_space(1))) unsigned int*)(g), \
                                     (__attribute__((address_space(3))) unsigned int*)(l), 16, 0, 0)

// XOR swizzle for LDS tiles with 512-byte row stride (row = byte>>9):
// spreads rows across banks; preserves 16B alignment (touches bits 4..6 only).
#define SWZ512(byte) ((byte) ^ (((((unsigned)(byte)) >> 9) & 7) << 4))

// fast sigmoid: native v_exp_f32 (+scale) and v_rcp_f32; ~1e-6 rel err, fine for bf16 outputs
__device__ __forceinline__ float sigm(float x){
    return __builtin_amdgcn_rcpf(1.f + __expf(-x));
}

// ---------------- depthwise 3x3 conv (pad 1), one (b,c) 64x64 plane per block ----------------
// float4 loads/stores; LDS tile [66][72]: interior at [1+y][4+x] (16B aligned), halo zeroed.
__global__ void dwconv3x3_k(const float* __restrict__ in, const float* __restrict__ w9,
                            const float* __restrict__ bias, float* __restrict__ out, int C)
{
    int bc = blockIdx.x;
    int c = bc % C;
    __shared__ float tile[66][72];
    const float* p = in + (size_t)bc * LPOS;
    int tid = threadIdx.x;
    // zero halo: rows 0 and 65 full; cols 3 and 68 for rows 1..64
    for (int i = tid; i < 144; i += 256) {
        int r = (i < 72) ? 0 : 65;
        int cc = i % 72;
        tile[r][cc] = 0.f;
    }
    if (tid < 64) { tile[tid+1][3] = 0.f; tile[tid+1][68] = 0.f; }
    // interior: 64 rows x 16 f32x4 per row, contiguous global loads
#pragma unroll
    for (int j = 0; j < 4; j++) {
        int f = tid + j*256;            // 0..1023
        int y = f >> 4, x4 = (f & 15) << 2;
        *(f32x4*)&tile[1+y][4+x4] = *(const f32x4*)&p[y*64 + x4];
    }
    __syncthreads();
    float w[9];
#pragma unroll
    for (int i = 0; i < 9; i++) w[i] = w9[c*9 + i];
    float bb = bias ? bias[c] : 0.f;
    float* q = out + (size_t)bc * LPOS;
#pragma unroll
    for (int j = 0; j < 4; j++) {
        int f = tid + j*256;
        int y = f >> 4, x4 = (f & 15) << 2;
        f32x4 acc = {bb, bb, bb, bb};
#pragma unroll
        for (int dy = 0; dy < 3; dy++) {
            const float* row = &tile[y+dy][3 + x4];   // 6-wide sliding window
            float t0 = row[0], t1 = row[1], t2 = row[2];
            float t3 = row[3], t4 = row[4], t5 = row[5];
            float w0 = w[dy*3], w1 = w[dy*3+1], w2 = w[dy*3+2];
            acc[0] += w0*t0 + w1*t1 + w2*t2;
            acc[1] += w0*t1 + w1*t2 + w2*t3;
            acc[2] += w0*t2 + w1*t3 + w2*t4;
            acc[3] += w0*t3 + w1*t4 + w2*t5;
        }
        *(f32x4*)&q[y*64 + x4] = acc;
    }
}

// ---- fused: x1 = (1-g)x + g*LN_dw1(conv);  xn = LN(x1) -> bf16 (C-major + pos-major) ----
// block (16,32): each thread 4 positions (f32x4) x 8 channels
__global__ __launch_bounds__(512)
void ln_x1xn_k(const float* __restrict__ conv, const float* __restrict__ xin,
               float* __restrict__ x1, bf16* __restrict__ xnC, bf16* __restrict__ xnT,
               const float* __restrict__ dww, const float* __restrict__ dwb,
               const float* __restrict__ g0,
               const float* __restrict__ lnw, const float* __restrict__ lnb)
{
    int b = blockIdx.x >> 6;
    int tx = threadIdx.x;            // 0..15
    int ty = threadIdx.y;            // 0..31
    int p0 = ((blockIdx.x & 63) << 6) + (tx << 2);
    __shared__ float rs[32][68], rs2[32][68];
    int tid = ty*16 + tx;
    f32x4 vals[8];
    f32x4 s = {0.f,0.f,0.f,0.f}, s2 = {0.f,0.f,0.f,0.f};
    size_t bi = ((size_t)b*256 + ty*8)*LPOS + p0;
#pragma unroll
    for (int i = 0; i < 8; i++) {
        f32x4 x = *(const f32x4*)&conv[bi + (size_t)i*LPOS];
        vals[i] = x; s += x; s2 += x*x;
    }
#pragma unroll
    for (int q = 0; q < 4; q++) { rs[ty][tx*4+q] = s[q]; rs2[ty][tx*4+q] = s2[q]; }
    __syncthreads();
    {
        int r = tid >> 6, cc = tid & 63;
        rs[r][cc]  = rs[r][cc]  + rs[r+8][cc]  + rs[r+16][cc]  + rs[r+24][cc];
        rs2[r][cc] = rs2[r][cc] + rs2[r+8][cc] + rs2[r+16][cc] + rs2[r+24][cc];
    }
    __syncthreads();
    f32x4 S = {0.f,0.f,0.f,0.f}, S2 = {0.f,0.f,0.f,0.f};
#pragma unroll
    for (int j = 0; j < 8; j++) {
        S  += *(const f32x4*)&rs[j][tx*4];
        S2 += *(const f32x4*)&rs2[j][tx*4];
    }
    f32x4 u, inv;
#pragma unroll
    for (int q = 0; q < 4; q++) {
        float uu = S[q]*(1.f/256.f);
        u[q] = uu;
        inv[q] = rsqrtf(S2[q]*(1.f/256.f) - uu*uu + 1e-5f);
    }
    __syncthreads();
    // pass 2: x1 = (1-g)x + g*LN(conv)
    s = (f32x4){0.f,0.f,0.f,0.f}; s2 = (f32x4){0.f,0.f,0.f,0.f};
#pragma unroll
    for (int i = 0; i < 8; i++) {
        int c = ty*8 + i;
        float w = dww[c], bbc = dwb[c];
        float g = sigm(g0[c]);
        f32x4 xv = *(const f32x4*)&xin[bi + (size_t)i*LPOS];
        f32x4 r;
#pragma unroll
        for (int q = 0; q < 4; q++) {
            float ln = w*((vals[i][q]-u[q])*inv[q]) + bbc;
            r[q] = (1.f-g)*xv[q] + g*ln;
        }
        vals[i] = r;
        *(f32x4*)&x1[bi + (size_t)i*LPOS] = r;
        s += r; s2 += r*r;
    }
#pragma unroll
    for (int q = 0; q < 4; q++) { rs[ty][tx*4+q] = s[q]; rs2[ty][tx*4+q] = s2[q]; }
    __syncthreads();
    {
        int r = tid >> 6, cc = tid & 63;
        rs[r][cc]  = rs[r][cc]  + rs[r+8][cc]  + rs[r+16][cc]  + rs[r+24][cc];
        rs2[r][cc] = rs2[r][cc] + rs2[r+8][cc] + rs2[r+16][cc] + rs2[r+24][cc];
    }
    __syncthreads();
    S = (f32x4){0.f,0.f,0.f,0.f}; S2 = (f32x4){0.f,0.f,0.f,0.f};
#pragma unroll
    for (int j = 0; j < 8; j++) {
        S  += *(const f32x4*)&rs[j][tx*4];
        S2 += *(const f32x4*)&rs2[j][tx*4];
    }
#pragma unroll
    for (int q = 0; q < 4; q++) {
        float uu = S[q]*(1.f/256.f);
        u[q] = uu;
        inv[q] = rsqrtf(S2[q]*(1.f/256.f) - uu*uu + 1e-5f);
    }
    bf16 tmp[32];   // [q][i]
#pragma unroll
    for (int i = 0; i < 8; i++) {
        int c = ty*8 + i;
        float w = lnw[c], bbc = lnb[c];
        bf16x4 o;
#pragma unroll
        for (int q = 0; q < 4; q++) {
            float xnv = w*((vals[i][q]-u[q])*inv[q]) + bbc;
            o[q] = (bf16)xnv;
            tmp[q*8+i] = (bf16)xnv;
        }
        *(bf16x4*)&xnC[bi + (size_t)i*LPOS] = o;
    }
#pragma unroll
    for (int q = 0; q < 4; q++) {
        bf16x8* dst = (bf16x8*)&xnT[((size_t)b*LPOS + p0 + q)*256 + ty*8];
        *dst = *(bf16x8*)&tmp[q*8];
    }
}

// ---- channel LN over C=256; mode 1: (1-g)*base + g*LN; optional pos-major bf16 auxT ----
// block (16,32): each thread 4 positions (f32x4) x 8 channels
__global__ __launch_bounds__(512)
void ln2d_k(const float* __restrict__ v, const float* __restrict__ base,
            float* __restrict__ out, const float* __restrict__ lnw,
            const float* __restrict__ lnb, const float* __restrict__ gate,
            bf16* __restrict__ auxT, int mode)
{
    int b = blockIdx.x >> 6;
    int tx = threadIdx.x;            // 0..15
    int ty = threadIdx.y;            // 0..31
    int p0 = ((blockIdx.x & 63) << 6) + (tx << 2);
    __shared__ float rs[32][68], rs2[32][68];
    int tid = ty*16 + tx;
    f32x4 vals[8];
    f32x4 s = {0.f,0.f,0.f,0.f}, s2 = {0.f,0.f,0.f,0.f};
    size_t bi = ((size_t)b*256 + ty*8)*LPOS + p0;
#pragma unroll
    for (int i = 0; i < 8; i++) {
        f32x4 x = *(const f32x4*)&v[bi + (size_t)i*LPOS];
        vals[i] = x; s += x; s2 += x*x;
    }
#pragma unroll
    for (int q = 0; q < 4; q++) { rs[ty][tx*4+q] = s[q]; rs2[ty][tx*4+q] = s2[q]; }
    __syncthreads();
    {
        int r = tid >> 6, cc = tid & 63;
        rs[r][cc]  = rs[r][cc]  + rs[r+8][cc]  + rs[r+16][cc]  + rs[r+24][cc];
        rs2[r][cc] = rs2[r][cc] + rs2[r+8][cc] + rs2[r+16][cc] + rs2[r+24][cc];
    }
    __syncthreads();
    f32x4 S = {0.f,0.f,0.f,0.f}, S2 = {0.f,0.f,0.f,0.f};
#pragma unroll
    for (int j = 0; j < 8; j++) {
        S  += *(const f32x4*)&rs[j][tx*4];
        S2 += *(const f32x4*)&rs2[j][tx*4];
    }
    f32x4 u, inv;
#pragma unroll
    for (int q = 0; q < 4; q++) {
        float uu = S[q]*(1.f/256.f);
        u[q] = uu;
        inv[q] = rsqrtf(S2[q]*(1.f/256.f) - uu*uu + 1e-5f);
    }
    bf16 tmp[32];   // [q][i]
#pragma unroll
    for (int i = 0; i < 8; i++) {
        int c = ty*8 + i;
        float w = lnw[c], bbc = lnb[c];
        f32x4 r;
        if (mode == 0) {
#pragma unroll
            for (int q = 0; q < 4; q++) r[q] = w*((vals[i][q]-u[q])*inv[q]) + bbc;
        } else {
            float g = sigm(gate[c]);
            f32x4 bs = *(const f32x4*)&base[bi + (size_t)i*LPOS];
#pragma unroll
            for (int q = 0; q < 4; q++) {
                float ln = w*((vals[i][q]-u[q])*inv[q]) + bbc;
                r[q] = (1.f-g)*bs[q] + g*ln;
            }
        }
        *(f32x4*)&out[bi + (size_t)i*LPOS] = r;
#pragma unroll
        for (int q = 0; q < 4; q++) tmp[q*8+i] = (bf16)r[q];
    }
    if (auxT) {
#pragma unroll
        for (int q = 0; q < 4; q++) {
            bf16x8* dst = (bf16x8*)&auxT[((size_t)b*LPOS + p0 + q)*256 + ty*8];
            *dst = *(bf16x8*)&tmp[q*8];
        }
    }
}

// ---------------- fp32 -> bf16 convert ----------------
__global__ void f2b_k(const float* __restrict__ in, bf16* __restrict__ out, int n)
{
    int i = blockIdx.x*256 + threadIdx.x;
    if (i < n) out[i] = (bf16)in[i];
}

// ---------------- bcdt_w [192][256] fp32 -> padded [256][256] bf16 (rows>=192 zero) ----------------
__global__ void pad_w_k(const float* __restrict__ w, bf16* __restrict__ out)
{
    int i = blockIdx.x*256 + threadIdx.x;   // 65536
    int r = i >> 8;
    out[i] = (r < 192) ? (bf16)w[(size_t)r*256 + (i & 255)] : (bf16)0.f;
}

// ---------------- Cm [b][64][4096] fp32 -> CmT [b][4096][64] bf16 ----------------
__global__ void transpose_cm_k(const float* __restrict__ Cm, bf16* __restrict__ CmT)
{
    int b = blockIdx.y;
    int l0 = blockIdx.x * 64;
    const float* src = Cm + (size_t)b * 192 * LPOS;
    bf16* dst = CmT + (size_t)b * LPOS * 64;
    __shared__ float t[64][65];
    int tid = threadIdx.x;
    for (int i = tid; i < 4096; i += 256) {
        int s = i >> 6, l = i & 63;
        t[s][l] = src[(size_t)s*LPOS + l0 + l];
    }
    __syncthreads();
    for (int i = tid; i < 4096; i += 256) {
        int l = i >> 6, s = i & 63;
        dst[(size_t)(l0+l)*64 + s] = (bf16)t[s][l];
    }
}

// ---------------- AB = softmax(dt + A[s]) * Bm -> bf16 ABb [b][64][L] ----------------
__global__ void softmax_ab_k(const float* __restrict__ bcdt2, bf16* __restrict__ ABb,
                             const float* __restrict__ Avec)
{
    int b = blockIdx.x >> 6, s = blockIdx.x & 63;
    size_t base = (size_t)b*192*LPOS;
    const f32x4* dt = (const f32x4*)(bcdt2 + base + (size_t)(128+s)*LPOS);
    const f32x4* Bm = (const f32x4*)(bcdt2 + base + (size_t)s*LPOS);
    bf16* outp = ABb + ((size_t)b*64 + s)*LPOS;
    int tid = threadIdx.x;
    float av = Avec[s];
    f32x4 v[4];
    float mx = -1e30f;
#pragma unroll
    for (int i = 0; i < 4; i++) {
        f32x4 x = dt[tid + (i<<8)];
#pragma unroll
        for (int q = 0; q < 4; q++) { x[q] += av; mx = fmaxf(mx, x[q]); }
        v[i] = x;
    }
    __shared__ float red[256];
    red[tid] = mx; __syncthreads();
    for (int o = 128; o > 0; o >>= 1) {
        if (tid < o) red[tid] = fmaxf(red[tid], red[tid+o]);
        __syncthreads();
    }
    mx = red[0];
    __syncthreads();
    float sum = 0.f;
#pragma unroll
    for (int i = 0; i < 4; i++)
#pragma unroll
        for (int q = 0; q < 4; q++) { v[i][q] = __expf(v[i][q]-mx); sum += v[i][q]; }
    red[tid] = sum; __syncthreads();
    for (int o = 128; o > 0; o >>= 1) {
        if (tid < o) red[tid] += red[tid+o];
        __syncthreads();
    }
    float rinv = __builtin_amdgcn_rcpf(red[0]);
#pragma unroll
    for (int i = 0; i < 4; i++) {
        f32x4 bm = Bm[tid + (i<<8)];
        bf16x4 o;
#pragma unroll
        for (int q = 0; q < 4; q++) o[q] = (bf16)(v[i][q] * rinv * bm[q]);
        ((bf16x4*)outp)[tid + (i<<8)] = o;
    }
}

// =====================================================================================
// Fused mixer tail: hz = hz_w@h + hz_b; hg = hp*silu(z); ho = outp_w@hg + outp_b -> bf16
// one block per batch, 512 threads (8 waves), MFMA. LDS: hT/hgT 32KB (swizzled) + hzs 64KB
// =====================================================================================
__global__ __launch_bounds__(512)
void mixer_tail_k(const float* __restrict__ h, const float* __restrict__ hz_w,
                  const float* __restrict__ hz_b, const float* __restrict__ outp_w,
                  const float* __restrict__ outp_b, bf16* __restrict__ hob16)
{
    __shared__ bf16 hT[64*256];     // 32KB: h^T (phase A/B), then hg^T (phase D/E); swizzled
    __shared__ bf16 hzs[512*64];    // 64KB: hz staging (bf16)
    int b = blockIdx.x;
    int tid = threadIdx.x;
    int lane = tid & 63, w = tid >> 6;      // 8 waves
    int fm = lane & 15, quad = lane >> 4;

    // ---- phase A: h [256][64] fp32 -> hT[n][k] bf16 swizzled ----
    const float* hb = h + (size_t)b*256*64;
#pragma unroll
    for (int j = 0; j < 8; j++) {
        int e4 = tid + j*512;           // one f32x4 each
        f32x4 v = *(const f32x4*)&hb[e4*4];
        int k = (e4*4) >> 6;            // 0..255
        int n = (e4*4) & 63;
#pragma unroll
        for (int q = 0; q < 4; q++) {
            int byte = (n+q)*512 + k*2;
            *(bf16*)((char*)hT + SWZ512(byte)) = (bf16)v[q];
        }
    }
    __syncthreads();

    // ---- phase B: hz = hz_w @ h  (M=512, N=64, K=256); wave w -> rows [w*64, w*64+64) ----
    int mw = w*64;
    f32x4 acc[4][4] = {};
#pragma unroll
    for (int ks = 0; ks < 8; ks++) {
        int k0 = ks*32;
        bf16x8 af[4], bfr[4];
#pragma unroll
        for (int i = 0; i < 4; i++) {
            const float* wp = &hz_w[(size_t)(mw + i*16 + fm)*256 + k0 + quad*8];
            f32x4 w0 = *(const f32x4*)wp;
            f32x4 w1 = *(const f32x4*)(wp + 4);
#pragma unroll
            for (int q = 0; q < 4; q++) { af[i][q] = (bf16)w0[q]; af[i][4+q] = (bf16)w1[q]; }
        }
#pragma unroll
        for (int j = 0; j < 4; j++) {
            int n = j*16 + fm;
            int byte = n*512 + (k0 + quad*8)*2;
            bfr[j] = *(const bf16x8*)((const char*)hT + SWZ512(byte));
        }
#pragma unroll
        for (int i = 0; i < 4; i++)
#pragma unroll
            for (int j = 0; j < 4; j++)
                acc[i][j] = __builtin_amdgcn_mfma_f32_16x16x32_bf16(af[i], bfr[j], acc[i][j], 0, 0, 0);
    }
    // ---- phase C: hz(+bias) -> hzs bf16 ----
#pragma unroll
    for (int i = 0; i < 4; i++)
#pragma unroll
        for (int r = 0; r < 4; r++) {
            int m = mw + i*16 + quad*4 + r;
            float bb = hz_b[m];
#pragma unroll
            for (int j = 0; j < 4; j++)
                hzs[m*64 + j*16 + fm] = (bf16)(acc[i][j][r] + bb);
        }
    __syncthreads();

    // ---- phase D: hg = hp*silu(z) -> hgT[n][k] (reuse hT buffer, swizzled) ----
    {
        int k = tid >> 1, n0 = (tid & 1) * 32;
#pragma unroll
        for (int c = 0; c < 4; c++) {
            bf16x8 hp = *(const bf16x8*)&hzs[k*64 + n0 + c*8];
            bf16x8 zz = *(const bf16x8*)&hzs[(k+256)*64 + n0 + c*8];
#pragma unroll
            for (int q = 0; q < 8; q++) {
                float z = (float)zz[q];
                float g = (float)hp[q] * z * sigm(z);
                int byte = (n0 + c*8 + q)*512 + k*2;
                *(bf16*)((char*)hT + SWZ512(byte)) = (bf16)g;
            }
        }
    }
    __syncthreads();

    // ---- phase E: ho = outp_w @ hg (M=256, N=64, K=256); wave w -> rows [w*32, w*32+32) ----
    int mw2 = w*32;
    f32x4 acc2[2][4] = {};
#pragma unroll
    for (int ks = 0; ks < 8; ks++) {
        int k0 = ks*32;
        bf16x8 af[2], bfr[4];
#pragma unroll
        for (int i = 0; i < 2; i++) {
            const float* wp = &outp_w[(size_t)(mw2 + i*16 + fm)*256 + k0 + quad*8];
            f32x4 w0 = *(const f32x4*)wp;
            f32x4 w1 = *(const f32x4*)(wp + 4);
#pragma unroll
            for (int q = 0; q < 4; q++) { af[i][q] = (bf16)w0[q]; af[i][4+q] = (bf16)w1[q]; }
        }
#pragma unroll
        for (int j = 0; j < 4; j++) {
            int n = j*16 + fm;
            int byte = n*512 + (k0 + quad*8)*2;
            bfr[j] = *(const bf16x8*)((const char*)hT + SWZ512(byte));
        }
#pragma unroll
        for (int i = 0; i < 2; i++)
#pragma unroll
            for (int j = 0; j < 4; j++)
                acc2[i][j] = __builtin_amdgcn_mfma_f32_16x16x32_bf16(af[i], bfr[j], acc2[i][j], 0, 0, 0);
    }
    bf16* ob = hob16 + (size_t)b*256*64;
#pragma unroll
    for (int i = 0; i < 2; i++)
#pragma unroll
        for (int r = 0; r < 4; r++) {
            int m = mw2 + i*16 + quad*4 + r;
            float bb = outp_b[m];
#pragma unroll
            for (int j = 0; j < 4; j++)
                ob[m*64 + j*16 + fm] = (bf16)(acc2[i][j][r] + bb);
        }
}

// =====================================================================================
// MFMA NT GEMM: D[m][n] = sum_k A[m][k]*B[n][k] (+bias[m]); 128x128 tile, BK=64
// stores guarded by m < mlimit.  OUT_BF16: 1 -> bf16 out, 0 -> fp32 out
// =====================================================================================
template<int OUT_BF16>
__global__ __launch_bounds__(256)
void gemm_nt_mfma(const bf16* __restrict__ A, const bf16* __restrict__ B,
                  void* __restrict__ C, const float* __restrict__ bias, int mlimit,
                  int K, int lda, int ldb, int ldc,
                  size_t abst, size_t bbst, size_t cbst)
{
    int b = blockIdx.z;
    const bf16* Ab = A + (size_t)b*abst;
    const bf16* Bb = B + (size_t)b*bbst;
    int m0 = blockIdx.y*128, n0 = blockIdx.x*128;
    __shared__ bf16 Asl[128*64];
    __shared__ bf16 Bsl[128*64];
    int tid = threadIdx.x;
    int lane = tid & 63;
    int w = tid >> 6;
    int wm = (w >> 1)*64, wn = (w & 1)*64;
    int fm = lane & 15, quad = lane >> 4;
    f32x4 acc[4][4] = {};
    for (int k0 = 0; k0 < K; k0 += 64) {
#pragma unroll
        for (int ii = 0; ii < 4; ii++) {
            int q = ii*256 + tid;
            int row = q >> 3, ko = (q & 7) << 3;
            GLOAD_LDS16(Ab + (size_t)(m0+row)*lda + k0 + ko, &Asl[q*8]);
            GLOAD_LDS16(Bb + (size_t)(n0+row)*ldb + k0 + ko, &Bsl[q*8]);
        }
        __syncthreads();
#pragma unroll
        for (int kk = 0; kk < 2; kk++) {
            bf16x8 af[4], bfr[4];
#pragma unroll
            for (int i = 0; i < 4; i++)
                af[i] = *(const bf16x8*)&Asl[(wm + i*16 + fm)*64 + kk*32 + quad*8];
#pragma unroll
            for (int j = 0; j < 4; j++)
                bfr[j] = *(const bf16x8*)&Bsl[(wn + j*16 + fm)*64 + kk*32 + quad*8];
#pragma unroll
            for (int i = 0; i < 4; i++)
#pragma unroll
                for (int j = 0; j < 4; j++)
                    acc[i][j] = __builtin_amdgcn_mfma_f32_16x16x32_bf16(af[i], bfr[j], acc[i][j], 0, 0, 0);
        }
        __syncthreads();
    }
    size_t cb = (size_t)b*cbst;
#pragma unroll
    for (int i = 0; i < 4; i++) {
#pragma unroll
        for (int r = 0; r < 4; r++) {
            int m = m0 + wm + i*16 + quad*4 + r;
            if (m >= mlimit) continue;
            float bb = bias ? bias[m] : 0.f;
#pragma unroll
            for (int j = 0; j < 4; j++) {
                int n = n0 + wn + j*16 + fm;
                float vv = acc[i][j][r] + bb;
                if (OUT_BF16) ((bf16*)C)[cb + (size_t)m*ldc + n] = (bf16)vv;
                else          ((float*)C)[cb + (size_t)m*ldc + n] = vv;
            }
        }
    }
}

// =====================================================================================
// fc1 GEMM + per-row LN stats: f1[pos][1024] bf16; stats[pos] += (sum, sumsq) over 1024
// A = x3t chunk [Z][4096][256], B = fc1_wb [1024][256]; grid (8, 32, Z)
// =====================================================================================
__global__ __launch_bounds__(256)
void gemm_fc1_stats(const bf16* __restrict__ A, const bf16* __restrict__ B,
                    bf16* __restrict__ C, float* __restrict__ stats)
{
    int z = blockIdx.z;
    const bf16* Ab = A + (size_t)z*LPOS*256;
    bf16* Cb = C + (size_t)z*LPOS*1024;
    int m0 = blockIdx.y*128, n0 = blockIdx.x*128;
    __shared__ bf16 Asl[128*64];
    __shared__ bf16 Bsl[128*64];
    int tid = threadIdx.x;
    int lane = tid & 63;
    int w = tid >> 6;
    int wm = (w >> 1)*64, wn = (w & 1)*64;
    int fm = lane & 15, quad = lane >> 4;
    f32x4 acc[4][4] = {};
    for (int k0 = 0; k0 < 256; k0 += 64) {
#pragma unroll
        for (int ii = 0; ii < 4; ii++) {
            int q = ii*256 + tid;
            int row = q >> 3, ko = (q & 7) << 3;
            GLOAD_LDS16(Ab + (size_t)(m0+row)*256 + k0 + ko, &Asl[q*8]);
            GLOAD_LDS16(B + (size_t)(n0+row)*256 + k0 + ko, &Bsl[q*8]);
        }
        __syncthreads();
#pragma unroll
        for (int kk = 0; kk < 2; kk++) {
            bf16x8 af[4], bfr[4];
#pragma unroll
            for (int i = 0; i < 4; i++)
                af[i] = *(const bf16x8*)&Asl[(wm + i*16 + fm)*64 + kk*32 + quad*8];
#pragma unroll
            for (int j = 0; j < 4; j++)
                bfr[j] = *(const bf16x8*)&Bsl[(wn + j*16 + fm)*64 + kk*32 + quad*8];
#pragma unroll
            for (int i = 0; i < 4; i++)
#pragma unroll
                for (int j = 0; j < 4; j++)
                    acc[i][j] = __builtin_amdgcn_mfma_f32_16x16x32_bf16(af[i], bfr[j], acc[i][j], 0, 0, 0);
        }
        __syncthreads();
    }
#pragma unroll
    for (int i = 0; i < 4; i++) {
#pragma unroll
        for (int r = 0; r < 4; r++) {
            int m = m0 + wm + i*16 + quad*4 + r;
            float s = 0.f, s2 = 0.f;
#pragma unroll
            for (int j = 0; j < 4; j++) {
                int n = n0 + wn + j*16 + fm;
                float vv = acc[i][j][r];
                Cb[(size_t)m*1024 + n] = (bf16)vv;
                s += vv; s2 += vv*vv;
            }
            // reduce over the 16 fm lanes (masks 1,2,4,8 stay within the 16-group)
#pragma unroll
            for (int msk = 1; msk <= 8; msk <<= 1) {
                s  += __shfl_xor(s, msk);
                s2 += __shfl_xor(s2, msk);
            }
            if (fm == 0) {
                atomicAdd(&stats[(size_t)(z*LPOS + m)*2 + 0], s);
                atomicAdd(&stats[(size_t)(z*LPOS + m)*2 + 1], s2);
            }
        }
    }
}

// =====================================================================================
// fc2 + fc1-LN/SiLU (in-LDS, from stats) + final LN + gated mix; direct fp32 out.
// TWO batches per block (z and z+8, sharing the A tile): full M=256, BN=64, K=1024,
// 512 threads (8 waves), grid (64,1,8) = 512 blocks, ~60KB LDS -> 2 blocks/CU resident.
// The fixed per-k-step barrier/latency cost is amortized over 2x MFMA work.
// LDS tiles bank-deswizzled as before (source-block XOR with row&7).
// =====================================================================================
__global__ __launch_bounds__(512)
void gemm_fc2_out(const bf16* __restrict__ A, const bf16* __restrict__ f1a,
                  const bf16* __restrict__ f1b, const float* __restrict__ stats,
                  const float* __restrict__ l1w, const float* __restrict__ l1b,
                  const float* __restrict__ x3, float* __restrict__ outp,
                  const float* __restrict__ lw, const float* __restrict__ lb,
                  const float* __restrict__ gate)
{
    int z0 = blockIdx.z;                    // batches z0 (f1a) and z0+8 (f1b)
    const bf16* Bb0 = f1a + (size_t)z0*LPOS*1024;
    const bf16* Bb1 = f1b + (size_t)z0*LPOS*1024;
    const float* x3b0 = x3 + (size_t)z0*256*LPOS;
    const float* x3b1 = x3 + (size_t)(z0+8)*256*LPOS;
    float* ob0 = outp + (size_t)z0*256*LPOS;
    float* ob1 = outp + (size_t)(z0+8)*256*LPOS;
    int n0 = blockIdx.x*64;
    __shared__ bf16 Asl[256*64];            // 32KB
    __shared__ bf16 Bsl0[64*64];            // 8KB
    __shared__ bf16 Bsl1[64*64];            // 8KB
    __shared__ float ps[2][4][64], ps2[2][4][64];   // 4KB
    __shared__ float wsl[1024], bsl[1024];          // 8KB
    int tid = threadIdx.x;
    int lane = tid & 63;
    int w = tid >> 6;                       // 0..7
    int wm = (w & 3)*64, wn = (w >> 2)*32;  // 4 m-groups x 2 n-halves
    int fm = lane & 15, quad = lane >> 4;
    for (int i = tid; i < 1024; i += 512) { wsl[i] = l1w[i]; bsl[i] = l1b[i]; }
    // per-thread B-row stats (row is K-invariant: brow = tid>>3)
    int brow = tid >> 3;
    int bko = (((tid & 7) ^ (brow & 7))) << 3;   // swizzled source block
    float sS0 = stats[(size_t)(z0*LPOS + n0 + brow)*2 + 0];
    float sQ0 = stats[(size_t)(z0*LPOS + n0 + brow)*2 + 1];
    float bu0 = sS0*(1.f/1024.f);
    float binv0 = rsqrtf(sQ0*(1.f/1024.f) - bu0*bu0 + 1e-5f);
    float sS1 = stats[(size_t)((z0+8)*LPOS + n0 + brow)*2 + 0];
    float sQ1 = stats[(size_t)((z0+8)*LPOS + n0 + brow)*2 + 1];
    float bu1 = sS1*(1.f/1024.f);
    float binv1 = rsqrtf(sQ1*(1.f/1024.f) - bu1*bu1 + 1e-5f);
    f32x4 acc0[4][2] = {};
    f32x4 acc1[4][2] = {};
    for (int k0 = 0; k0 < 1024; k0 += 64) {
#pragma unroll
        for (int ii = 0; ii < 4; ii++) {    // A: 256 rows x 64 cols = 2048 x 16B (swz source)
            int q = ii*512 + tid;
            int row = q >> 3, ko = (((q & 7) ^ (row & 7))) << 3;
            GLOAD_LDS16(A + (size_t)row*1024 + k0 + ko, &Asl[q*8]);
        }
        // B tiles: 64 rows x 64 cols = 512 x 16B each, one per thread (raw f1, swz source)
        GLOAD_LDS16(Bb0 + (size_t)(n0+brow)*1024 + k0 + bko, &Bsl0[tid*8]);
        GLOAD_LDS16(Bb1 + (size_t)(n0+brow)*1024 + k0 + bko, &Bsl1[tid*8]);
        __syncthreads();
        // in-place LN+SiLU on this thread's own 16B of Bsl0/Bsl1 (hold global block bko)
        {
            bf16x8 v0 = *(const bf16x8*)&Bsl0[tid*8];
            bf16x8 v1 = *(const bf16x8*)&Bsl1[tid*8];
            bf16x8 o0, o1;
#pragma unroll
            for (int e = 0; e < 8; e++) {
                int k = k0 + bko + e;
                float wk = wsl[k], bk = bsl[k];
                float xx0 = ((float)v0[e] - bu0)*binv0;
                xx0 = wk*xx0 + bk;
                o0[e] = (bf16)(xx0*sigm(xx0));
                float xx1 = ((float)v1[e] - bu1)*binv1;
                xx1 = wk*xx1 + bk;
                o1[e] = (bf16)(xx1*sigm(xx1));
            }
            *(bf16x8*)&Bsl0[tid*8] = o0;
            *(bf16x8*)&Bsl1[tid*8] = o1;
        }
        __syncthreads();
#pragma unroll
        for (int kk = 0; kk < 2; kk++) {
            bf16x8 af[4], bfr0[2], bfr1[2];
#pragma unroll
            for (int i = 0; i < 4; i++) {
                int R = wm + i*16 + fm;
                af[i] = *(const bf16x8*)&Asl[R*64 + (((kk*4 + quad) ^ (R & 7)))*8];
            }
#pragma unroll
            for (int j = 0; j < 2; j++) {
                int R = wn + j*16 + fm;
                int blk = (((kk*4 + quad) ^ (R & 7)))*8;
                bfr0[j] = *(const bf16x8*)&Bsl0[R*64 + blk];
                bfr1[j] = *(const bf16x8*)&Bsl1[R*64 + blk];
            }
#pragma unroll
            for (int i = 0; i < 4; i++)
#pragma unroll
                for (int j = 0; j < 2; j++) {
                    acc0[i][j] = __builtin_amdgcn_mfma_f32_16x16x32_bf16(af[i], bfr0[j], acc0[i][j], 0, 0, 0);
                    acc1[i][j] = __builtin_amdgcn_mfma_f32_16x16x32_bf16(af[i], bfr1[j], acc1[i][j], 0, 0, 0);
                }
        }
        __syncthreads();
    }
    // per-column stats over M=256 for both batches
#pragma unroll
    for (int j = 0; j < 2; j++) {
        float s0 = 0.f, s20 = 0.f, s1 = 0.f, s21 = 0.f;
#pragma unroll
        for (int i = 0; i < 4; i++)
#pragma unroll
            for (int r = 0; r < 4; r++) {
                float v0 = acc0[i][j][r]; s0 += v0; s20 += v0*v0;
                float v1 = acc1[i][j][r]; s1 += v1; s21 += v1*v1;
            }
        s0 += __shfl_xor(s0, 16);  s20 += __shfl_xor(s20, 16);
        s0 += __shfl_xor(s0, 32);  s20 += __shfl_xor(s20, 32);
        s1 += __shfl_xor(s1, 16);  s21 += __shfl_xor(s21, 16);
        s1 += __shfl_xor(s1, 32);  s21 += __shfl_xor(s21, 32);
        if (quad == 0) {
            int n = wn + j*16 + fm;
            ps[0][w & 3][n] = s0;  ps2[0][w & 3][n] = s20;
            ps[1][w & 3][n] = s1;  ps2[1][w & 3][n] = s21;
        }
    }
    __syncthreads();
    float us0[2], iv0[2], us1[2], iv1[2];
#pragma unroll
    for (int j = 0; j < 2; j++) {
        int n = wn + j*16 + fm;
        float S0 = ps[0][0][n] + ps[0][1][n] + ps[0][2][n] + ps[0][3][n];
        float Q0 = ps2[0][0][n] + ps2[0][1][n] + ps2[0][2][n] + ps2[0][3][n];
        float u0 = S0*(1.f/256.f);
        us0[j] = u0;
        iv0[j] = rsqrtf(Q0*(1.f/256.f) - u0*u0 + 1e-5f);
        float S1 = ps[1][0][n] + ps[1][1][n] + ps[1][2][n] + ps[1][3][n];
        float Q1 = ps2[1][0][n] + ps2[1][1][n] + ps2[1][2][n] + ps2[1][3][n];
        float u1 = S1*(1.f/256.f);
        us1[j] = u1;
        iv1[j] = rsqrtf(Q1*(1.f/256.f) - u1*u1 + 1e-5f);
    }
#pragma unroll
    for (int i = 0; i < 4; i++) {
#pragma unroll
        for (int r = 0; r < 4; r++) {
            int m = wm + i*16 + quad*4 + r;
            float g = sigm(gate[m]);
            float lwm = lw[m], lbm = lb[m];
#pragma unroll
            for (int j = 0; j < 2; j++) {
                int n = n0 + wn + j*16 + fm;
                size_t idx = (size_t)m*LPOS + n;
                float ln0 = lwm*((acc0[i][j][r]-us0[j])*iv0[j]) + lbm;
                ob0[idx] = (1.f-g)*x3b0[idx] + g*ln0;
                float ln1 = lwm*((acc1[i][j][r]-us1[j])*iv1[j]) + lbm;
                ob1[idx] = (1.f-g)*x3b1[idx] + g*ln1;
            }
        }
    }
}

// =====================================================================================
// h-GEMM: h[b][d][s] += sum_l xnC[b][d][l]*ABb[b][s][l]; BM=128, BN=64, split-K atomic
// =====================================================================================
__global__ __launch_bounds__(256)
void gemm_h_mfma(const bf16* __restrict__ xnC, const bf16* __restrict__ ABb,
                 float* __restrict__ h, int Kchunk)
{
    int b = blockIdx.z;
    const bf16* Ab = xnC + (size_t)b*256*LPOS;
    const bf16* Bb = ABb + (size_t)b*64*LPOS;
    float* Cb = h + (size_t)b*256*64;
    int m0 = blockIdx.y*128;
    int kbase = blockIdx.x*Kchunk;
    __shared__ bf16 Asl[128*64];
    __shared__ bf16 Bsl[64*64];
    int tid = threadIdx.x;
    int lane = tid & 63;
    int w = tid >> 6;
    int wm = (w >> 1)*64, wn = (w & 1)*32;
    int fm = lane & 15, quad = lane >> 4;
    f32x4 acc[4][2] = {};
    for (int k0 = kbase; k0 < kbase + Kchunk; k0 += 64) {
#pragma unroll
        for (int ii = 0; ii < 4; ii++) {
            int q = ii*256 + tid;
            int row = q >> 3, ko = (q & 7) << 3;
            GLOAD_LDS16(Ab + (size_t)(m0+row)*LPOS + k0 + ko, &Asl[q*8]);
        }
#pragma unroll
        for (int ii = 0; ii < 2; ii++) {
            int q = ii*256 + tid;
            int row = q >> 3, ko = (q & 7) << 3;
            GLOAD_LDS16(Bb + (size_t)row*LPOS + k0 + ko, &Bsl[q*8]);
        }
        __syncthreads();
#pragma unroll
        for (int kk = 0; kk < 2; kk++) {
            bf16x8 af[4], bfr[2];
#pragma unroll
            for (int i = 0; i < 4; i++)
                af[i] = *(const bf16x8*)&Asl[(wm + i*16 + fm)*64 + kk*32 + quad*8];
#pragma unroll
            for (int j = 0; j < 2; j++)
                bfr[j] = *(const bf16x8*)&Bsl[(wn + j*16 + fm)*64 + kk*32 + quad*8];
#pragma unroll
            for (int i = 0; i < 4; i++)
#pragma unroll
                for (int j = 0; j < 2; j++)
                    acc[i][j] = __builtin_amdgcn_mfma_f32_16x16x32_bf16(af[i], bfr[j], acc[i][j], 0, 0, 0);
        }
        __syncthreads();
    }
#pragma unroll
    for (int i = 0; i < 4; i++)
#pragma unroll
        for (int r = 0; r < 4; r++) {
            int m = m0 + wm + i*16 + quad*4 + r;
#pragma unroll
            for (int j = 0; j < 2; j++) {
                int n = wn + j*16 + fm;
                atomicAdd(&Cb[(size_t)m*64 + n], acc[i][j][r]);
            }
        }
}

// =====================================================================================
// mixer out: x2[b][o][l] = (1-g)*x1 + g*( ho@Cm + xn*Dp ); xn read as bf16
// =====================================================================================
__global__ __launch_bounds__(256)
void mixer_out_mfma(const bf16* __restrict__ hoB, const bf16* __restrict__ CmT,
                    const bf16* __restrict__ xnC, float* __restrict__ x,
                    const float* __restrict__ Dp, const float* __restrict__ gate)
{
    int b = blockIdx.z;
    const bf16* Ab = hoB + (size_t)b*(256*64);
    const bf16* Bb = CmT + (size_t)b*((size_t)LPOS*64);
    int m0 = blockIdx.y*128, n0 = blockIdx.x*128;
    __shared__ bf16 Asl[128*64];
    __shared__ bf16 Bsl[128*64];
    int tid = threadIdx.x;
    int lane = tid & 63;
    int w = tid >> 6;
    int wm = (w >> 1)*64, wn = (w & 1)*64;
    int fm = lane & 15, quad = lane >> 4;
    f32x4 acc[4][4] = {};
#pragma unroll
    for (int ii = 0; ii < 4; ii++) {
        int q = ii*256 + tid;
        int row = q >> 3, ko = (q & 7) << 3;
        GLOAD_LDS16(Ab + (size_t)(m0+row)*64 + ko, &Asl[q*8]);
        GLOAD_LDS16(Bb + (size_t)(n0+row)*64 + ko, &Bsl[q*8]);
    }
    __syncthreads();
#pragma unroll
    for (int kk = 0; kk < 2; kk++) {
        bf16x8 af[4], bfr[4];
#pragma unroll
        for (int i = 0; i < 4; i++)
            af[i] = *(const bf16x8*)&Asl[(wm + i*16 + fm)*64 + kk*32 + quad*8];
#pragma unroll
        for (int j = 0; j < 4; j++)
            bfr[j] = *(const bf16x8*)&Bsl[(wn + j*16 + fm)*64 + kk*32 + quad*8];
#pragma unroll
        for (int i = 0; i < 4; i++)
#pragma unroll
            for (int j = 0; j < 4; j++)
                acc[i][j] = __builtin_amdgcn_mfma_f32_16x16x32_bf16(af[i], bfr[j], acc[i][j], 0, 0, 0);
    }
#pragma unroll
    for (int i = 0; i < 4; i++) {
#pragma unroll
        for (int r = 0; r < 4; r++) {
            int m = m0 + wm + i*16 + quad*4 + r;
            float g = sigm(gate[m]);
            float dp = Dp[m];
#pragma unroll
            for (int j = 0; j < 4; j++) {
                int n = n0 + wn + j*16 + fm;
                size_t idx = ((size_t)b*256 + m)*LPOS + n;
                float y = acc[i][j][r] + (float)xnC[idx]*dp;
                x[idx] = (1.f-g)*x[idx] + g*y;
            }
        }
    }
}

extern "C" void kernel_launch(void* const* d_in, const int* in_sizes, int n_in,
                              void* d_out, int out_size, void* d_ws, size_t ws_size,
                              hipStream_t stream)
{
    const float* x        = (const float*)d_in[0];
    const float* alpha    = (const float*)d_in[1];
    const float* ln_w     = (const float*)d_in[2];
    const float* ln_b     = (const float*)d_in[3];
    const float* dw1_w    = (const float*)d_in[4];
    const float* dw1_ln_w = (const float*)d_in[5];
    const float* dw1_ln_b = (const float*)d_in[6];
    const float* dw2_w    = (const float*)d_in[7];
    const float* dw2_ln_w = (const float*)d_in[8];
    const float* dw2_ln_b = (const float*)d_in[9];
    const float* bcdt_w   = (const float*)d_in[10];
    const float* bcdt_b   = (const float*)d_in[11];
    const float* dwm_w    = (const float*)d_in[12];
    const float* dwm_b    = (const float*)d_in[13];
    const float* hz_w     = (const float*)d_in[14];
    const float* hz_b     = (const float*)d_in[15];
    const float* outp_w   = (const float*)d_in[16];
    const float* outp_b   = (const float*)d_in[17];
    const float* Avec     = (const float*)d_in[18];
    const float* Dp       = (const float*)d_in[19];
    const float* fc1_w    = (const float*)d_in[20];
    const float* fc1_ln_w = (const float*)d_in[21];
    const float* fc1_ln_b = (const float*)d_in[22];
    const float* fc2_w    = (const float*)d_in[23];
    const float* fc2_ln_w = (const float*)d_in[24];
    const float* fc2_ln_b = (const float*)d_in[25];

    float* outp  = (float*)d_out;
    float* h_out = outp + (size_t)NB*256*LPOS;

    float* ws   = (float*)d_ws;
    float* bufA = ws;                                   // 64MB: conv tmp / bcdt / CmT / ABb / f1a
    float* bufB = bufA + (size_t)NB*256*LPOS;           // 64MB: x1 / x2 / x3
    float* bufC = bufB + (size_t)NB*256*LPOS;           // 64MB: xnC + xnT bf16, then f1b
    float* bufD = bufC + (size_t)NB*256*LPOS;           // 48MB: bcdt2, then x3t + small bf16 bufs
    float* hzb  = bufD + (size_t)NB*192*LPOS;           // 2MB (wpad overlay)

    // overlays
    bf16* CmT     = (bf16*)bufA;                        // 8MB, alive 5b..11
    bf16* ABb     = (bf16*)(bufA + 8*1024*1024);        // 8MB at byte-offset 32MB, alive 6..7
    bf16* xnC     = (bf16*)bufC;                        // 33.5MB channel-major xn
    bf16* xnT     = xnC + (size_t)NB*256*LPOS;          // 33.5MB position-major xn
    bf16* f1a     = (bf16*)bufA;                        // step 14: batches 0-7 f1 (64MiB)
    bf16* f1b     = (bf16*)bufC;                        // step 14: batches 8-15 f1 (64MiB)
    bf16* x3t     = (bf16*)bufD;                        // 33.5MB pos-major x3 (bcdt2 dead)
    bf16* fc1_wb  = (bf16*)(bufD + 9000000);            // byte-offset 36MB (past x3t)
    bf16* fc2_wb  = (bf16*)(bufD + 9200000);
    bf16* hob16   = (bf16*)(bufD + 9400000);
    float* stats  = bufD + 10000000;                    // 16*4096*2 fp32 = 512KB
    bf16* wpad    = (bf16*)hzb;                         // 128KB, alive steps 3b..4

    dim3 blk256(256);
    dim3 blkLN(16, 32);

    // 1. conv1(x) -> bufA
    dwconv3x3_k<<<dim3(NB*256), blk256, 0, stream>>>(x, dw1_w, nullptr, bufA, 256);
    // 2. fused: x1 -> bufB (fp32), xn -> xnC bf16 + xnT bf16
    ln_x1xn_k<<<dim3(NB*64), blkLN, 0, stream>>>(bufA, x, bufB, xnC, xnT,
                                                 dw1_ln_w, dw1_ln_b, alpha + 0, ln_w, ln_b);
    // 3b. padded bf16 bcdt weights
    pad_w_k<<<dim3(256), blk256, 0, stream>>>(bcdt_w, wpad);
    // 4. bcdt = bcdt_w @ xn + b -> bufA (192 rows compact, MFMA)
    gemm_nt_mfma<0><<<dim3(32, 2, NB), blk256, 0, stream>>>(
        wpad, xnT, (void*)bufA, bcdt_b, 192, 256, 256, 256, LPOS,
        0, (size_t)LPOS*256, (size_t)192*LPOS);
    // 5. convm(bcdt) -> bufD
    dwconv3x3_k<<<dim3(NB*192), blk256, 0, stream>>>(bufA, dwm_w, dwm_b, bufD, 192);
    // 5b. CmT = transpose(Cm) bf16
    transpose_cm_k<<<dim3(64, NB), blk256, 0, stream>>>(bufD + (size_t)64*LPOS, CmT);
    // 6. AB = softmax(dt+A)*Bm -> ABb bf16
    softmax_ab_k<<<dim3(NB*64), blk256, 0, stream>>>(bufD, ABb, Avec);
    // 6b. zero h region
    hipMemsetAsync(h_out, 0, (size_t)NB*256*64*sizeof(float), stream);
    // 7. h = xn . AB^T (MFMA, split-K 8, atomicAdd) -> 256 blocks = 1/CU
    gemm_h_mfma<<<dim3(8, 2, NB), blk256, 0, stream>>>(xnC, ABb, h_out, 512);
    // 8-10. fused mixer tail: hz -> hg -> ho (bf16 out), one block per batch
    mixer_tail_k<<<dim3(NB), dim3(512), 0, stream>>>(h_out, hz_w, hz_b, outp_w, outp_b, hob16);
    // 10b. bf16 weight converts for FFN
    f2b_k<<<dim3(1024), blk256, 0, stream>>>(fc1_w, fc1_wb, 1024*256);
    f2b_k<<<dim3(1024), blk256, 0, stream>>>(fc2_w, fc2_wb, 256*1024);
    // 11. x2 = (1-a1)x1 + a1*(ho@Cm + xn*Dp) (in-place bufB), MFMA
    mixer_out_mfma<<<dim3(32, 2, NB), blk256, 0, stream>>>(hob16, CmT, xnC, bufB, Dp, alpha + 256);
    // 12. conv2(x2) -> bufA
    dwconv3x3_k<<<dim3(NB*256), blk256, 0, stream>>>(bufB, dw2_w, nullptr, bufA, 256);
    // 13. x3 = (1-a2)x2 + a2*LN(conv2) (in-place bufB) + x3t bf16 pos-major
    ln2d_k<<<dim3(NB*64), blkLN, 0, stream>>>(bufA, bufB, bufB, dw2_ln_w, dw2_ln_b, alpha + 512, x3t, 1);
    // 14. FFN over all 16 batches: 2x fc1+stats (8 batches each into f1a/f1b),
    //     then ONE fc2_out: 2 batches/block (z, z+8 share the A tile), grid (64,1,8)
    hipMemsetAsync(stats, 0, (size_t)16*LPOS*2*sizeof(float), stream);
    gemm_fc1_stats<<<dim3(8, 32, 8), blk256, 0, stream>>>(x3t, fc1_wb, f1a, stats);
    gemm_fc1_stats<<<dim3(8, 32, 8), blk256, 0, stream>>>(x3t + (size_t)8*LPOS*256, fc1_wb, f1b,
                                                          stats + (size_t)8*LPOS*2);
    gemm_fc2_out<<<dim3(64, 1, 8), dim3(512), 0, stream>>>(
        fc2_wb, f1a, f1b, stats, fc1_ln_w, fc1_ln_b, bufB, outp,
        fc2_ln_w, fc2_ln_b, alpha + 768);
}

// Round 10
// 615.210 us; speedup vs baseline: 1.0192x; 1.0192x over previous
//
#include <hip/hip_runtime.h>
#include <math.h>

#define LPOS 4096   // H*W
#define NB 16       // batch

typedef __bf16 bf16;
typedef __bf16 bf16x8 __attribute__((ext_vector_type(8)));
typedef __bf16 bf16x4 __attribute__((ext_vector_type(4)));
typedef float f32x4 __attribute__((ext_vector_type(4)));

#define GLOAD_LDS16(g, l) \
    __builtin_amdgcn_global_load_lds((const __attribute__((address_space(1))) unsigned int*)(g), \
                                     (__attribute__((address_space(3))) unsigned int*)(l), 16, 0, 0)

// XOR swizzle for LDS tiles with 512-byte row stride (row = byte>>9):
// spreads rows across banks; preserves 16B alignment (touches bits 4..6 only).
#define SWZ512(byte) ((byte) ^ (((((unsigned)(byte)) >> 9) & 7) << 4))

// fast sigmoid: native v_exp_f32 (+scale) and v_rcp_f32; ~1e-6 rel err, fine for bf16 outputs
__device__ __forceinline__ float sigm(float x){
    return __builtin_amdgcn_rcpf(1.f + __expf(-x));
}

// ---------------- depthwise 3x3 conv (pad 1), one (b,c) 64x64 plane per block ----------------
// float4 loads/stores; LDS tile [66][72]: interior at [1+y][4+x] (16B aligned), halo zeroed.
__global__ void dwconv3x3_k(const float* __restrict__ in, const float* __restrict__ w9,
                            const float* __restrict__ bias, float* __restrict__ out, int C)
{
    int bc = blockIdx.x;
    int c = bc % C;
    __shared__ float tile[66][72];
    const float* p = in + (size_t)bc * LPOS;
    int tid = threadIdx.x;
    // zero halo: rows 0 and 65 full; cols 3 and 68 for rows 1..64
    for (int i = tid; i < 144; i += 256) {
        int r = (i < 72) ? 0 : 65;
        int cc = i % 72;
        tile[r][cc] = 0.f;
    }
    if (tid < 64) { tile[tid+1][3] = 0.f; tile[tid+1][68] = 0.f; }
    // interior: 64 rows x 16 f32x4 per row, contiguous global loads
#pragma unroll
    for (int j = 0; j < 4; j++) {
        int f = tid + j*256;            // 0..1023
        int y = f >> 4, x4 = (f & 15) << 2;
        *(f32x4*)&tile[1+y][4+x4] = *(const f32x4*)&p[y*64 + x4];
    }
    __syncthreads();
    float w[9];
#pragma unroll
    for (int i = 0; i < 9; i++) w[i] = w9[c*9 + i];
    float bb = bias ? bias[c] : 0.f;
    float* q = out + (size_t)bc * LPOS;
#pragma unroll
    for (int j = 0; j < 4; j++) {
        int f = tid + j*256;
        int y = f >> 4, x4 = (f & 15) << 2;
        f32x4 acc = {bb, bb, bb, bb};
#pragma unroll
        for (int dy = 0; dy < 3; dy++) {
            const float* row = &tile[y+dy][3 + x4];   // 6-wide sliding window
            float t0 = row[0], t1 = row[1], t2 = row[2];
            float t3 = row[3], t4 = row[4], t5 = row[5];
            float w0 = w[dy*3], w1 = w[dy*3+1], w2 = w[dy*3+2];
            acc[0] += w0*t0 + w1*t1 + w2*t2;
            acc[1] += w0*t1 + w1*t2 + w2*t3;
            acc[2] += w0*t2 + w1*t3 + w2*t4;
            acc[3] += w0*t3 + w1*t4 + w2*t5;
        }
        *(f32x4*)&q[y*64 + x4] = acc;
    }
}

// ---- fused: x1 = (1-g)x + g*LN_dw1(conv);  xn = LN(x1) -> bf16 (C-major + pos-major) ----
// block (16,32): each thread 4 positions (f32x4) x 8 channels
__global__ __launch_bounds__(512)
void ln_x1xn_k(const float* __restrict__ conv, const float* __restrict__ xin,
               float* __restrict__ x1, bf16* __restrict__ xnC, bf16* __restrict__ xnT,
               const float* __restrict__ dww, const float* __restrict__ dwb,
               const float* __restrict__ g0,
               const float* __restrict__ lnw, const float* __restrict__ lnb)
{
    int b = blockIdx.x >> 6;
    int tx = threadIdx.x;            // 0..15
    int ty = threadIdx.y;            // 0..31
    int p0 = ((blockIdx.x & 63) << 6) + (tx << 2);
    __shared__ float rs[32][68], rs2[32][68];
    int tid = ty*16 + tx;
    f32x4 vals[8];
    f32x4 s = {0.f,0.f,0.f,0.f}, s2 = {0.f,0.f,0.f,0.f};
    size_t bi = ((size_t)b*256 + ty*8)*LPOS + p0;
#pragma unroll
    for (int i = 0; i < 8; i++) {
        f32x4 x = *(const f32x4*)&conv[bi + (size_t)i*LPOS];
        vals[i] = x; s += x; s2 += x*x;
    }
#pragma unroll
    for (int q = 0; q < 4; q++) { rs[ty][tx*4+q] = s[q]; rs2[ty][tx*4+q] = s2[q]; }
    __syncthreads();
    {
        int r = tid >> 6, cc = tid & 63;
        rs[r][cc]  = rs[r][cc]  + rs[r+8][cc]  + rs[r+16][cc]  + rs[r+24][cc];
        rs2[r][cc] = rs2[r][cc] + rs2[r+8][cc] + rs2[r+16][cc] + rs2[r+24][cc];
    }
    __syncthreads();
    f32x4 S = {0.f,0.f,0.f,0.f}, S2 = {0.f,0.f,0.f,0.f};
#pragma unroll
    for (int j = 0; j < 8; j++) {
        S  += *(const f32x4*)&rs[j][tx*4];
        S2 += *(const f32x4*)&rs2[j][tx*4];
    }
    f32x4 u, inv;
#pragma unroll
    for (int q = 0; q < 4; q++) {
        float uu = S[q]*(1.f/256.f);
        u[q] = uu;
        inv[q] = rsqrtf(S2[q]*(1.f/256.f) - uu*uu + 1e-5f);
    }
    __syncthreads();
    // pass 2: x1 = (1-g)x + g*LN(conv)
    s = (f32x4){0.f,0.f,0.f,0.f}; s2 = (f32x4){0.f,0.f,0.f,0.f};
#pragma unroll
    for (int i = 0; i < 8; i++) {
        int c = ty*8 + i;
        float w = dww[c], bbc = dwb[c];
        float g = sigm(g0[c]);
        f32x4 xv = *(const f32x4*)&xin[bi + (size_t)i*LPOS];
        f32x4 r;
#pragma unroll
        for (int q = 0; q < 4; q++) {
            float ln = w*((vals[i][q]-u[q])*inv[q]) + bbc;
            r[q] = (1.f-g)*xv[q] + g*ln;
        }
        vals[i] = r;
        *(f32x4*)&x1[bi + (size_t)i*LPOS] = r;
        s += r; s2 += r*r;
    }
#pragma unroll
    for (int q = 0; q < 4; q++) { rs[ty][tx*4+q] = s[q]; rs2[ty][tx*4+q] = s2[q]; }
    __syncthreads();
    {
        int r = tid >> 6, cc = tid & 63;
        rs[r][cc]  = rs[r][cc]  + rs[r+8][cc]  + rs[r+16][cc]  + rs[r+24][cc];
        rs2[r][cc] = rs2[r][cc] + rs2[r+8][cc] + rs2[r+16][cc] + rs2[r+24][cc];
    }
    __syncthreads();
    S = (f32x4){0.f,0.f,0.f,0.f}; S2 = (f32x4){0.f,0.f,0.f,0.f};
#pragma unroll
    for (int j = 0; j < 8; j++) {
        S  += *(const f32x4*)&rs[j][tx*4];
        S2 += *(const f32x4*)&rs2[j][tx*4];
    }
#pragma unroll
    for (int q = 0; q < 4; q++) {
        float uu = S[q]*(1.f/256.f);
        u[q] = uu;
        inv[q] = rsqrtf(S2[q]*(1.f/256.f) - uu*uu + 1e-5f);
    }
    bf16 tmp[32];   // [q][i]
#pragma unroll
    for (int i = 0; i < 8; i++) {
        int c = ty*8 + i;
        float w = lnw[c], bbc = lnb[c];
        bf16x4 o;
#pragma unroll
        for (int q = 0; q < 4; q++) {
            float xnv = w*((vals[i][q]-u[q])*inv[q]) + bbc;
            o[q] = (bf16)xnv;
            tmp[q*8+i] = (bf16)xnv;
        }
        *(bf16x4*)&xnC[bi + (size_t)i*LPOS] = o;
    }
#pragma unroll
    for (int q = 0; q < 4; q++) {
        bf16x8* dst = (bf16x8*)&xnT[((size_t)b*LPOS + p0 + q)*256 + ty*8];
        *dst = *(bf16x8*)&tmp[q*8];
    }
}

// ---- channel LN over C=256; mode 1: (1-g)*base + g*LN; optional pos-major bf16 auxT ----
// block (16,32): each thread 4 positions (f32x4) x 8 channels
__global__ __launch_bounds__(512)
void ln2d_k(const float* __restrict__ v, const float* __restrict__ base,
            float* __restrict__ out, const float* __restrict__ lnw,
            const float* __restrict__ lnb, const float* __restrict__ gate,
            bf16* __restrict__ auxT, int mode)
{
    int b = blockIdx.x >> 6;
    int tx = threadIdx.x;            // 0..15
    int ty = threadIdx.y;            // 0..31
    int p0 = ((blockIdx.x & 63) << 6) + (tx << 2);
    __shared__ float rs[32][68], rs2[32][68];
    int tid = ty*16 + tx;
    f32x4 vals[8];
    f32x4 s = {0.f,0.f,0.f,0.f}, s2 = {0.f,0.f,0.f,0.f};
    size_t bi = ((size_t)b*256 + ty*8)*LPOS + p0;
#pragma unroll
    for (int i = 0; i < 8; i++) {
        f32x4 x = *(const f32x4*)&v[bi + (size_t)i*LPOS];
        vals[i] = x; s += x; s2 += x*x;
    }
#pragma unroll
    for (int q = 0; q < 4; q++) { rs[ty][tx*4+q] = s[q]; rs2[ty][tx*4+q] = s2[q]; }
    __syncthreads();
    {
        int r = tid >> 6, cc = tid & 63;
        rs[r][cc]  = rs[r][cc]  + rs[r+8][cc]  + rs[r+16][cc]  + rs[r+24][cc];
        rs2[r][cc] = rs2[r][cc] + rs2[r+8][cc] + rs2[r+16][cc] + rs2[r+24][cc];
    }
    __syncthreads();
    f32x4 S = {0.f,0.f,0.f,0.f}, S2 = {0.f,0.f,0.f,0.f};
#pragma unroll
    for (int j = 0; j < 8; j++) {
        S  += *(const f32x4*)&rs[j][tx*4];
        S2 += *(const f32x4*)&rs2[j][tx*4];
    }
    f32x4 u, inv;
#pragma unroll
    for (int q = 0; q < 4; q++) {
        float uu = S[q]*(1.f/256.f);
        u[q] = uu;
        inv[q] = rsqrtf(S2[q]*(1.f/256.f) - uu*uu + 1e-5f);
    }
    bf16 tmp[32];   // [q][i]
#pragma unroll
    for (int i = 0; i < 8; i++) {
        int c = ty*8 + i;
        float w = lnw[c], bbc = lnb[c];
        f32x4 r;
        if (mode == 0) {
#pragma unroll
            for (int q = 0; q < 4; q++) r[q] = w*((vals[i][q]-u[q])*inv[q]) + bbc;
        } else {
            float g = sigm(gate[c]);
            f32x4 bs = *(const f32x4*)&base[bi + (size_t)i*LPOS];
#pragma unroll
            for (int q = 0; q < 4; q++) {
                float ln = w*((vals[i][q]-u[q])*inv[q]) + bbc;
                r[q] = (1.f-g)*bs[q] + g*ln;
            }
        }
        *(f32x4*)&out[bi + (size_t)i*LPOS] = r;
#pragma unroll
        for (int q = 0; q < 4; q++) tmp[q*8+i] = (bf16)r[q];
    }
    if (auxT) {
#pragma unroll
        for (int q = 0; q < 4; q++) {
            bf16x8* dst = (bf16x8*)&auxT[((size_t)b*LPOS + p0 + q)*256 + ty*8];
            *dst = *(bf16x8*)&tmp[q*8];
        }
    }
}

// ---------------- fp32 -> bf16 convert ----------------
__global__ void f2b_k(const float* __restrict__ in, bf16* __restrict__ out, int n)
{
    int i = blockIdx.x*256 + threadIdx.x;
    if (i < n) out[i] = (bf16)in[i];
}

// ---------------- bcdt_w [192][256] fp32 -> padded [256][256] bf16 (rows>=192 zero) ----------------
__global__ void pad_w_k(const float* __restrict__ w, bf16* __restrict__ out)
{
    int i = blockIdx.x*256 + threadIdx.x;   // 65536
    int r = i >> 8;
    out[i] = (r < 192) ? (bf16)w[(size_t)r*256 + (i & 255)] : (bf16)0.f;
}

// ---------------- Cm [b][64][4096] fp32 -> CmT [b][4096][64] bf16 ----------------
__global__ void transpose_cm_k(const float* __restrict__ Cm, bf16* __restrict__ CmT)
{
    int b = blockIdx.y;
    int l0 = blockIdx.x * 64;
    const float* src = Cm + (size_t)b * 192 * LPOS;
    bf16* dst = CmT + (size_t)b * LPOS * 64;
    __shared__ float t[64][65];
    int tid = threadIdx.x;
    for (int i = tid; i < 4096; i += 256) {
        int s = i >> 6, l = i & 63;
        t[s][l] = src[(size_t)s*LPOS + l0 + l];
    }
    __syncthreads();
    for (int i = tid; i < 4096; i += 256) {
        int l = i >> 6, s = i & 63;
        dst[(size_t)(l0+l)*64 + s] = (bf16)t[s][l];
    }
}

// ---------------- AB = softmax(dt + A[s]) * Bm -> bf16 ABb [b][64][L] ----------------
__global__ void softmax_ab_k(const float* __restrict__ bcdt2, bf16* __restrict__ ABb,
                             const float* __restrict__ Avec)
{
    int b = blockIdx.x >> 6, s = blockIdx.x & 63;
    size_t base = (size_t)b*192*LPOS;
    const f32x4* dt = (const f32x4*)(bcdt2 + base + (size_t)(128+s)*LPOS);
    const f32x4* Bm = (const f32x4*)(bcdt2 + base + (size_t)s*LPOS);
    bf16* outp = ABb + ((size_t)b*64 + s)*LPOS;
    int tid = threadIdx.x;
    float av = Avec[s];
    f32x4 v[4];
    float mx = -1e30f;
#pragma unroll
    for (int i = 0; i < 4; i++) {
        f32x4 x = dt[tid + (i<<8)];
#pragma unroll
        for (int q = 0; q < 4; q++) { x[q] += av; mx = fmaxf(mx, x[q]); }
        v[i] = x;
    }
    __shared__ float red[256];
    red[tid] = mx; __syncthreads();
    for (int o = 128; o > 0; o >>= 1) {
        if (tid < o) red[tid] = fmaxf(red[tid], red[tid+o]);
        __syncthreads();
    }
    mx = red[0];
    __syncthreads();
    float sum = 0.f;
#pragma unroll
    for (int i = 0; i < 4; i++)
#pragma unroll
        for (int q = 0; q < 4; q++) { v[i][q] = __expf(v[i][q]-mx); sum += v[i][q]; }
    red[tid] = sum; __syncthreads();
    for (int o = 128; o > 0; o >>= 1) {
        if (tid < o) red[tid] += red[tid+o];
        __syncthreads();
    }
    float rinv = __builtin_amdgcn_rcpf(red[0]);
#pragma unroll
    for (int i = 0; i < 4; i++) {
        f32x4 bm = Bm[tid + (i<<8)];
        bf16x4 o;
#pragma unroll
        for (int q = 0; q < 4; q++) o[q] = (bf16)(v[i][q] * rinv * bm[q]);
        ((bf16x4*)outp)[tid + (i<<8)] = o;
    }
}

// =====================================================================================
// Fused mixer tail: hz = hz_w@h + hz_b; hg = hp*silu(z); ho = outp_w@hg + outp_b -> bf16
// one block per batch, 512 threads (8 waves), MFMA. LDS: hT/hgT 32KB (swizzled) + hzs 64KB
// =====================================================================================
__global__ __launch_bounds__(512)
void mixer_tail_k(const float* __restrict__ h, const float* __restrict__ hz_w,
                  const float* __restrict__ hz_b, const float* __restrict__ outp_w,
                  const float* __restrict__ outp_b, bf16* __restrict__ hob16)
{
    __shared__ bf16 hT[64*256];     // 32KB: h^T (phase A/B), then hg^T (phase D/E); swizzled
    __shared__ bf16 hzs[512*64];    // 64KB: hz staging (bf16)
    int b = blockIdx.x;
    int tid = threadIdx.x;
    int lane = tid & 63, w = tid >> 6;      // 8 waves
    int fm = lane & 15, quad = lane >> 4;

    // ---- phase A: h [256][64] fp32 -> hT[n][k] bf16 swizzled ----
    const float* hb = h + (size_t)b*256*64;
#pragma unroll
    for (int j = 0; j < 8; j++) {
        int e4 = tid + j*512;           // one f32x4 each
        f32x4 v = *(const f32x4*)&hb[e4*4];
        int k = (e4*4) >> 6;            // 0..255
        int n = (e4*4) & 63;
#pragma unroll
        for (int q = 0; q < 4; q++) {
            int byte = (n+q)*512 + k*2;
            *(bf16*)((char*)hT + SWZ512(byte)) = (bf16)v[q];
        }
    }
    __syncthreads();

    // ---- phase B: hz = hz_w @ h  (M=512, N=64, K=256); wave w -> rows [w*64, w*64+64) ----
    int mw = w*64;
    f32x4 acc[4][4] = {};
#pragma unroll
    for (int ks = 0; ks < 8; ks++) {
        int k0 = ks*32;
        bf16x8 af[4], bfr[4];
#pragma unroll
        for (int i = 0; i < 4; i++) {
            const float* wp = &hz_w[(size_t)(mw + i*16 + fm)*256 + k0 + quad*8];
            f32x4 w0 = *(const f32x4*)wp;
            f32x4 w1 = *(const f32x4*)(wp + 4);
#pragma unroll
            for (int q = 0; q < 4; q++) { af[i][q] = (bf16)w0[q]; af[i][4+q] = (bf16)w1[q]; }
        }
#pragma unroll
        for (int j = 0; j < 4; j++) {
            int n = j*16 + fm;
            int byte = n*512 + (k0 + quad*8)*2;
            bfr[j] = *(const bf16x8*)((const char*)hT + SWZ512(byte));
        }
#pragma unroll
        for (int i = 0; i < 4; i++)
#pragma unroll
            for (int j = 0; j < 4; j++)
                acc[i][j] = __builtin_amdgcn_mfma_f32_16x16x32_bf16(af[i], bfr[j], acc[i][j], 0, 0, 0);
    }
    // ---- phase C: hz(+bias) -> hzs bf16 ----
#pragma unroll
    for (int i = 0; i < 4; i++)
#pragma unroll
        for (int r = 0; r < 4; r++) {
            int m = mw + i*16 + quad*4 + r;
            float bb = hz_b[m];
#pragma unroll
            for (int j = 0; j < 4; j++)
                hzs[m*64 + j*16 + fm] = (bf16)(acc[i][j][r] + bb);
        }
    __syncthreads();

    // ---- phase D: hg = hp*silu(z) -> hgT[n][k] (reuse hT buffer, swizzled) ----
    {
        int k = tid >> 1, n0 = (tid & 1) * 32;
#pragma unroll
        for (int c = 0; c < 4; c++) {
            bf16x8 hp = *(const bf16x8*)&hzs[k*64 + n0 + c*8];
            bf16x8 zz = *(const bf16x8*)&hzs[(k+256)*64 + n0 + c*8];
#pragma unroll
            for (int q = 0; q < 8; q++) {
                float z = (float)zz[q];
                float g = (float)hp[q] * z * sigm(z);
                int byte = (n0 + c*8 + q)*512 + k*2;
                *(bf16*)((char*)hT + SWZ512(byte)) = (bf16)g;
            }
        }
    }
    __syncthreads();

    // ---- phase E: ho = outp_w @ hg (M=256, N=64, K=256); wave w -> rows [w*32, w*32+32) ----
    int mw2 = w*32;
    f32x4 acc2[2][4] = {};
#pragma unroll
    for (int ks = 0; ks < 8; ks++) {
        int k0 = ks*32;
        bf16x8 af[2], bfr[4];
#pragma unroll
        for (int i = 0; i < 2; i++) {
            const float* wp = &outp_w[(size_t)(mw2 + i*16 + fm)*256 + k0 + quad*8];
            f32x4 w0 = *(const f32x4*)wp;
            f32x4 w1 = *(const f32x4*)(wp + 4);
#pragma unroll
            for (int q = 0; q < 4; q++) { af[i][q] = (bf16)w0[q]; af[i][4+q] = (bf16)w1[q]; }
        }
#pragma unroll
        for (int j = 0; j < 4; j++) {
            int n = j*16 + fm;
            int byte = n*512 + (k0 + quad*8)*2;
            bfr[j] = *(const bf16x8*)((const char*)hT + SWZ512(byte));
        }
#pragma unroll
        for (int i = 0; i < 2; i++)
#pragma unroll
            for (int j = 0; j < 4; j++)
                acc2[i][j] = __builtin_amdgcn_mfma_f32_16x16x32_bf16(af[i], bfr[j], acc2[i][j], 0, 0, 0);
    }
    bf16* ob = hob16 + (size_t)b*256*64;
#pragma unroll
    for (int i = 0; i < 2; i++)
#pragma unroll
        for (int r = 0; r < 4; r++) {
            int m = mw2 + i*16 + quad*4 + r;
            float bb = outp_b[m];
#pragma unroll
            for (int j = 0; j < 4; j++)
                ob[m*64 + j*16 + fm] = (bf16)(acc2[i][j][r] + bb);
        }
}

// =====================================================================================
// MFMA NT GEMM: D[m][n] = sum_k A[m][k]*B[n][k] (+bias[m]); 128x128 tile, BK=64
// stores guarded by m < mlimit.  OUT_BF16: 1 -> bf16 out, 0 -> fp32 out
// =====================================================================================
template<int OUT_BF16>
__global__ __launch_bounds__(256)
void gemm_nt_mfma(const bf16* __restrict__ A, const bf16* __restrict__ B,
                  void* __restrict__ C, const float* __restrict__ bias, int mlimit,
                  int K, int lda, int ldb, int ldc,
                  size_t abst, size_t bbst, size_t cbst)
{
    int b = blockIdx.z;
    const bf16* Ab = A + (size_t)b*abst;
    const bf16* Bb = B + (size_t)b*bbst;
    int m0 = blockIdx.y*128, n0 = blockIdx.x*128;
    __shared__ bf16 Asl[128*64];
    __shared__ bf16 Bsl[128*64];
    int tid = threadIdx.x;
    int lane = tid & 63;
    int w = tid >> 6;
    int wm = (w >> 1)*64, wn = (w & 1)*64;
    int fm = lane & 15, quad = lane >> 4;
    f32x4 acc[4][4] = {};
    for (int k0 = 0; k0 < K; k0 += 64) {
#pragma unroll
        for (int ii = 0; ii < 4; ii++) {
            int q = ii*256 + tid;
            int row = q >> 3, ko = (q & 7) << 3;
            GLOAD_LDS16(Ab + (size_t)(m0+row)*lda + k0 + ko, &Asl[q*8]);
            GLOAD_LDS16(Bb + (size_t)(n0+row)*ldb + k0 + ko, &Bsl[q*8]);
        }
        __syncthreads();
#pragma unroll
        for (int kk = 0; kk < 2; kk++) {
            bf16x8 af[4], bfr[4];
#pragma unroll
            for (int i = 0; i < 4; i++)
                af[i] = *(const bf16x8*)&Asl[(wm + i*16 + fm)*64 + kk*32 + quad*8];
#pragma unroll
            for (int j = 0; j < 4; j++)
                bfr[j] = *(const bf16x8*)&Bsl[(wn + j*16 + fm)*64 + kk*32 + quad*8];
#pragma unroll
            for (int i = 0; i < 4; i++)
#pragma unroll
                for (int j = 0; j < 4; j++)
                    acc[i][j] = __builtin_amdgcn_mfma_f32_16x16x32_bf16(af[i], bfr[j], acc[i][j], 0, 0, 0);
        }
        __syncthreads();
    }
    size_t cb = (size_t)b*cbst;
#pragma unroll
    for (int i = 0; i < 4; i++) {
#pragma unroll
        for (int r = 0; r < 4; r++) {
            int m = m0 + wm + i*16 + quad*4 + r;
            if (m >= mlimit) continue;
            float bb = bias ? bias[m] : 0.f;
#pragma unroll
            for (int j = 0; j < 4; j++) {
                int n = n0 + wn + j*16 + fm;
                float vv = acc[i][j][r] + bb;
                if (OUT_BF16) ((bf16*)C)[cb + (size_t)m*ldc + n] = (bf16)vv;
                else          ((float*)C)[cb + (size_t)m*ldc + n] = vv;
            }
        }
    }
}

// =====================================================================================
// fc1 GEMM + per-row LN stats: f1[pos][1024] bf16; stats[pos] += (sum, sumsq) over 1024
// A = x3t chunk [Z][4096][256], B = fc1_wb [1024][256]; grid (8, 32, Z)
// =====================================================================================
__global__ __launch_bounds__(256)
void gemm_fc1_stats(const bf16* __restrict__ A, const bf16* __restrict__ B,
                    bf16* __restrict__ C, float* __restrict__ stats)
{
    int z = blockIdx.z;
    const bf16* Ab = A + (size_t)z*LPOS*256;
    bf16* Cb = C + (size_t)z*LPOS*1024;
    int m0 = blockIdx.y*128, n0 = blockIdx.x*128;
    __shared__ bf16 Asl[128*64];
    __shared__ bf16 Bsl[128*64];
    int tid = threadIdx.x;
    int lane = tid & 63;
    int w = tid >> 6;
    int wm = (w >> 1)*64, wn = (w & 1)*64;
    int fm = lane & 15, quad = lane >> 4;
    f32x4 acc[4][4] = {};
    for (int k0 = 0; k0 < 256; k0 += 64) {
#pragma unroll
        for (int ii = 0; ii < 4; ii++) {
            int q = ii*256 + tid;
            int row = q >> 3, ko = (q & 7) << 3;
            GLOAD_LDS16(Ab + (size_t)(m0+row)*256 + k0 + ko, &Asl[q*8]);
            GLOAD_LDS16(B + (size_t)(n0+row)*256 + k0 + ko, &Bsl[q*8]);
        }
        __syncthreads();
#pragma unroll
        for (int kk = 0; kk < 2; kk++) {
            bf16x8 af[4], bfr[4];
#pragma unroll
            for (int i = 0; i < 4; i++)
                af[i] = *(const bf16x8*)&Asl[(wm + i*16 + fm)*64 + kk*32 + quad*8];
#pragma unroll
            for (int j = 0; j < 4; j++)
                bfr[j] = *(const bf16x8*)&Bsl[(wn + j*16 + fm)*64 + kk*32 + quad*8];
#pragma unroll
            for (int i = 0; i < 4; i++)
#pragma unroll
                for (int j = 0; j < 4; j++)
                    acc[i][j] = __builtin_amdgcn_mfma_f32_16x16x32_bf16(af[i], bfr[j], acc[i][j], 0, 0, 0);
        }
        __syncthreads();
    }
#pragma unroll
    for (int i = 0; i < 4; i++) {
#pragma unroll
        for (int r = 0; r < 4; r++) {
            int m = m0 + wm + i*16 + quad*4 + r;
            float s = 0.f, s2 = 0.f;
#pragma unroll
            for (int j = 0; j < 4; j++) {
                int n = n0 + wn + j*16 + fm;
                float vv = acc[i][j][r];
                Cb[(size_t)m*1024 + n] = (bf16)vv;
                s += vv; s2 += vv*vv;
            }
            // reduce over the 16 fm lanes (masks 1,2,4,8 stay within the 16-group)
#pragma unroll
            for (int msk = 1; msk <= 8; msk <<= 1) {
                s  += __shfl_xor(s, msk);
                s2 += __shfl_xor(s2, msk);
            }
            if (fm == 0) {
                atomicAdd(&stats[(size_t)(z*LPOS + m)*2 + 0], s);
                atomicAdd(&stats[(size_t)(z*LPOS + m)*2 + 1], s2);
            }
        }
    }
}

// =====================================================================================
// fc2 + fc1-LN/SiLU (reg-staged B, from stats) + final LN + gated mix; direct fp32 out.
// Full M=256 per block; BN=64, K=1024, 512 threads (8 waves), grid (64,1,16).
// z 0..15 spans two f1 sub-buffers (f1a: z<8, f1b: z>=8); stats indexed by z directly.
// Per k-step: issue A global_load_lds; load B 16B global->reg (latency overlaps A);
// LN+SiLU in registers; ds_write; then ONE barrier -> MFMA -> barrier (2 barriers,
// no in-LDS read-modify-write). LDS tiles bank-deswizzled via source-block XOR (row&7);
// reads index block ((kk*4+quad)^(row&7)). 51KB LDS, ~44 VGPR.
// =====================================================================================
__global__ __launch_bounds__(512)
void gemm_fc2_out(const bf16* __restrict__ A, const bf16* __restrict__ f1a,
                  const bf16* __restrict__ f1b, const float* __restrict__ stats,
                  const float* __restrict__ l1w, const float* __restrict__ l1b,
                  const float* __restrict__ x3, float* __restrict__ outp,
                  const float* __restrict__ lw, const float* __restrict__ lb,
                  const float* __restrict__ gate)
{
    int z = blockIdx.z;
    const bf16* Bb = (z < 8 ? f1a + (size_t)z*LPOS*1024 : f1b + (size_t)(z-8)*LPOS*1024);
    const float* x3b = x3 + (size_t)z*256*LPOS;
    float* ob = outp + (size_t)z*256*LPOS;
    int n0 = blockIdx.x*64;
    __shared__ bf16 Asl[256*64];    // 32KB
    __shared__ bf16 Bsl[64*64];     // 8KB
    __shared__ float ps[4][64], ps2[4][64];     // 2KB
    __shared__ float wsl[1024], bsl[1024];      // 8KB
    int tid = threadIdx.x;
    int lane = tid & 63;
    int w = tid >> 6;                       // 0..7
    int wm = (w & 3)*64, wn = (w >> 2)*32;  // 4 m-groups x 2 n-halves
    int fm = lane & 15, quad = lane >> 4;
    for (int i = tid; i < 1024; i += 512) { wsl[i] = l1w[i]; bsl[i] = l1b[i]; }
    // per-thread B-row stats (row is K-invariant: brow = tid>>3)
    int brow = tid >> 3;
    int bko = (((tid & 7) ^ (brow & 7))) << 3;   // swizzled source block
    float sS = stats[(size_t)(z*LPOS + n0 + brow)*2 + 0];
    float sQ = stats[(size_t)(z*LPOS + n0 + brow)*2 + 1];
    float bu = sS*(1.f/1024.f);
    float binv = rsqrtf(sQ*(1.f/1024.f) - bu*bu + 1e-5f);
    __syncthreads();   // wsl/bsl ready before first use
    f32x4 acc[4][2] = {};
    for (int k0 = 0; k0 < 1024; k0 += 64) {
#pragma unroll
        for (int ii = 0; ii < 4; ii++) {    // A: 256 rows x 64 cols = 2048 x 16B (swz source)
            int q = ii*512 + tid;
            int row = q >> 3, ko = (((q & 7) ^ (row & 7))) << 3;
            GLOAD_LDS16(A + (size_t)row*1024 + k0 + ko, &Asl[q*8]);
        }
        // B: 16B/thread global->reg (overlaps A issue), LN+SiLU in regs, ds_write
        {
            bf16x8 v = *(const bf16x8*)&Bb[(size_t)(n0+brow)*1024 + k0 + bko];
            bf16x8 o;
#pragma unroll
            for (int e = 0; e < 8; e++) {
                int k = k0 + bko + e;
                float xx = ((float)v[e] - bu)*binv;
                xx = wsl[k]*xx + bsl[k];
                o[e] = (bf16)(xx*sigm(xx));
            }
            *(bf16x8*)&Bsl[tid*8] = o;
        }
        __syncthreads();
#pragma unroll
        for (int kk = 0; kk < 2; kk++) {
            bf16x8 af[4], bfr[2];
#pragma unroll
            for (int i = 0; i < 4; i++) {
                int R = wm + i*16 + fm;
                af[i] = *(const bf16x8*)&Asl[R*64 + (((kk*4 + quad) ^ (R & 7)))*8];
            }
#pragma unroll
            for (int j = 0; j < 2; j++) {
                int R = wn + j*16 + fm;
                bfr[j] = *(const bf16x8*)&Bsl[R*64 + (((kk*4 + quad) ^ (R & 7)))*8];
            }
#pragma unroll
            for (int i = 0; i < 4; i++)
#pragma unroll
                for (int j = 0; j < 2; j++)
                    acc[i][j] = __builtin_amdgcn_mfma_f32_16x16x32_bf16(af[i], bfr[j], acc[i][j], 0, 0, 0);
        }
        __syncthreads();
    }
    // per-column stats over M=256: in-thread 16 + shfl over quads, combine 4 m-groups in LDS
#pragma unroll
    for (int j = 0; j < 2; j++) {
        float s = 0.f, s2 = 0.f;
#pragma unroll
        for (int i = 0; i < 4; i++)
#pragma unroll
            for (int r = 0; r < 4; r++) { float v = acc[i][j][r]; s += v; s2 += v*v; }
        s  += __shfl_xor(s, 16);  s2 += __shfl_xor(s2, 16);
        s  += __shfl_xor(s, 32);  s2 += __shfl_xor(s2, 32);
        if (quad == 0) {
            int n = wn + j*16 + fm;
            ps[w & 3][n] = s;
            ps2[w & 3][n] = s2;
        }
    }
    __syncthreads();
    float us[2], iv[2];
#pragma unroll
    for (int j = 0; j < 2; j++) {
        int n = wn + j*16 + fm;
        float S  = ps[0][n] + ps[1][n] + ps[2][n] + ps[3][n];
        float S2 = ps2[0][n] + ps2[1][n] + ps2[2][n] + ps2[3][n];
        float u = S*(1.f/256.f);
        us[j] = u;
        iv[j] = rsqrtf(S2*(1.f/256.f) - u*u + 1e-5f);
    }
#pragma unroll
    for (int i = 0; i < 4; i++) {
#pragma unroll
        for (int r = 0; r < 4; r++) {
            int m = wm + i*16 + quad*4 + r;
            float g = sigm(gate[m]);
            float lwm = lw[m], lbm = lb[m];
#pragma unroll
            for (int j = 0; j < 2; j++) {
                int n = n0 + wn + j*16 + fm;
                size_t idx = (size_t)m*LPOS + n;
                float ln = lwm*((acc[i][j][r]-us[j])*iv[j]) + lbm;
                ob[idx] = (1.f-g)*x3b[idx] + g*ln;
            }
        }
    }
}

// =====================================================================================
// h-GEMM: h[b][d][s] += sum_l xnC[b][d][l]*ABb[b][s][l]; BM=128, BN=64, split-K atomic
// =====================================================================================
__global__ __launch_bounds__(256)
void gemm_h_mfma(const bf16* __restrict__ xnC, const bf16* __restrict__ ABb,
                 float* __restrict__ h, int Kchunk)
{
    int b = blockIdx.z;
    const bf16* Ab = xnC + (size_t)b*256*LPOS;
    const bf16* Bb = ABb + (size_t)b*64*LPOS;
    float* Cb = h + (size_t)b*256*64;
    int m0 = blockIdx.y*128;
    int kbase = blockIdx.x*Kchunk;
    __shared__ bf16 Asl[128*64];
    __shared__ bf16 Bsl[64*64];
    int tid = threadIdx.x;
    int lane = tid & 63;
    int w = tid >> 6;
    int wm = (w >> 1)*64, wn = (w & 1)*32;
    int fm = lane & 15, quad = lane >> 4;
    f32x4 acc[4][2] = {};
    for (int k0 = kbase; k0 < kbase + Kchunk; k0 += 64) {
#pragma unroll
        for (int ii = 0; ii < 4; ii++) {
            int q = ii*256 + tid;
            int row = q >> 3, ko = (q & 7) << 3;
            GLOAD_LDS16(Ab + (size_t)(m0+row)*LPOS + k0 + ko, &Asl[q*8]);
        }
#pragma unroll
        for (int ii = 0; ii < 2; ii++) {
            int q = ii*256 + tid;
            int row = q >> 3, ko = (q & 7) << 3;
            GLOAD_LDS16(Bb + (size_t)row*LPOS + k0 + ko, &Bsl[q*8]);
        }
        __syncthreads();
#pragma unroll
        for (int kk = 0; kk < 2; kk++) {
            bf16x8 af[4], bfr[2];
#pragma unroll
            for (int i = 0; i < 4; i++)
                af[i] = *(const bf16x8*)&Asl[(wm + i*16 + fm)*64 + kk*32 + quad*8];
#pragma unroll
            for (int j = 0; j < 2; j++)
                bfr[j] = *(const bf16x8*)&Bsl[(wn + j*16 + fm)*64 + kk*32 + quad*8];
#pragma unroll
            for (int i = 0; i < 4; i++)
#pragma unroll
                for (int j = 0; j < 2; j++)
                    acc[i][j] = __builtin_amdgcn_mfma_f32_16x16x32_bf16(af[i], bfr[j], acc[i][j], 0, 0, 0);
        }
        __syncthreads();
    }
#pragma unroll
    for (int i = 0; i < 4; i++)
#pragma unroll
        for (int r = 0; r < 4; r++) {
            int m = m0 + wm + i*16 + quad*4 + r;
#pragma unroll
            for (int j = 0; j < 2; j++) {
                int n = wn + j*16 + fm;
                atomicAdd(&Cb[(size_t)m*64 + n], acc[i][j][r]);
            }
        }
}

// =====================================================================================
// mixer out: x2[b][o][l] = (1-g)*x1 + g*( ho@Cm + xn*Dp ); xn read as bf16
// =====================================================================================
__global__ __launch_bounds__(256)
void mixer_out_mfma(const bf16* __restrict__ hoB, const bf16* __restrict__ CmT,
                    const bf16* __restrict__ xnC, float* __restrict__ x,
                    const float* __restrict__ Dp, const float* __restrict__ gate)
{
    int b = blockIdx.z;
    const bf16* Ab = hoB + (size_t)b*(256*64);
    const bf16* Bb = CmT + (size_t)b*((size_t)LPOS*64);
    int m0 = blockIdx.y*128, n0 = blockIdx.x*128;
    __shared__ bf16 Asl[128*64];
    __shared__ bf16 Bsl[128*64];
    int tid = threadIdx.x;
    int lane = tid & 63;
    int w = tid >> 6;
    int wm = (w >> 1)*64, wn = (w & 1)*64;
    int fm = lane & 15, quad = lane >> 4;
    f32x4 acc[4][4] = {};
#pragma unroll
    for (int ii = 0; ii < 4; ii++) {
        int q = ii*256 + tid;
        int row = q >> 3, ko = (q & 7) << 3;
        GLOAD_LDS16(Ab + (size_t)(m0+row)*64 + ko, &Asl[q*8]);
        GLOAD_LDS16(Bb + (size_t)(n0+row)*64 + ko, &Bsl[q*8]);
    }
    __syncthreads();
#pragma unroll
    for (int kk = 0; kk < 2; kk++) {
        bf16x8 af[4], bfr[4];
#pragma unroll
        for (int i = 0; i < 4; i++)
            af[i] = *(const bf16x8*)&Asl[(wm + i*16 + fm)*64 + kk*32 + quad*8];
#pragma unroll
        for (int j = 0; j < 4; j++)
            bfr[j] = *(const bf16x8*)&Bsl[(wn + j*16 + fm)*64 + kk*32 + quad*8];
#pragma unroll
        for (int i = 0; i < 4; i++)
#pragma unroll
            for (int j = 0; j < 4; j++)
                acc[i][j] = __builtin_amdgcn_mfma_f32_16x16x32_bf16(af[i], bfr[j], acc[i][j], 0, 0, 0);
    }
#pragma unroll
    for (int i = 0; i < 4; i++) {
#pragma unroll
        for (int r = 0; r < 4; r++) {
            int m = m0 + wm + i*16 + quad*4 + r;
            float g = sigm(gate[m]);
            float dp = Dp[m];
#pragma unroll
            for (int j = 0; j < 4; j++) {
                int n = n0 + wn + j*16 + fm;
                size_t idx = ((size_t)b*256 + m)*LPOS + n;
                float y = acc[i][j][r] + (float)xnC[idx]*dp;
                x[idx] = (1.f-g)*x[idx] + g*y;
            }
        }
    }
}

extern "C" void kernel_launch(void* const* d_in, const int* in_sizes, int n_in,
                              void* d_out, int out_size, void* d_ws, size_t ws_size,
                              hipStream_t stream)
{
    const float* x        = (const float*)d_in[0];
    const float* alpha    = (const float*)d_in[1];
    const float* ln_w     = (const float*)d_in[2];
    const float* ln_b     = (const float*)d_in[3];
    const float* dw1_w    = (const float*)d_in[4];
    const float* dw1_ln_w = (const float*)d_in[5];
    const float* dw1_ln_b = (const float*)d_in[6];
    const float* dw2_w    = (const float*)d_in[7];
    const float* dw2_ln_w = (const float*)d_in[8];
    const float* dw2_ln_b = (const float*)d_in[9];
    const float* bcdt_w   = (const float*)d_in[10];
    const float* bcdt_b   = (const float*)d_in[11];
    const float* dwm_w    = (const float*)d_in[12];
    const float* dwm_b    = (const float*)d_in[13];
    const float* hz_w     = (const float*)d_in[14];
    const float* hz_b     = (const float*)d_in[15];
    const float* outp_w   = (const float*)d_in[16];
    const float* outp_b   = (const float*)d_in[17];
    const float* Avec     = (const float*)d_in[18];
    const float* Dp       = (const float*)d_in[19];
    const float* fc1_w    = (const float*)d_in[20];
    const float* fc1_ln_w = (const float*)d_in[21];
    const float* fc1_ln_b = (const float*)d_in[22];
    const float* fc2_w    = (const float*)d_in[23];
    const float* fc2_ln_w = (const float*)d_in[24];
    const float* fc2_ln_b = (const float*)d_in[25];

    float* outp  = (float*)d_out;
    float* h_out = outp + (size_t)NB*256*LPOS;

    float* ws   = (float*)d_ws;
    float* bufA = ws;                                   // 64MB: conv tmp / bcdt / CmT / ABb / f1a
    float* bufB = bufA + (size_t)NB*256*LPOS;           // 64MB: x1 / x2 / x3
    float* bufC = bufB + (size_t)NB*256*LPOS;           // 64MB: xnC + xnT bf16, then f1b
    float* bufD = bufC + (size_t)NB*256*LPOS;           // 48MB: bcdt2, then x3t + small bf16 bufs
    float* hzb  = bufD + (size_t)NB*192*LPOS;           // 2MB (wpad overlay)

    // overlays
    bf16* CmT     = (bf16*)bufA;                        // 8MB, alive 5b..11
    bf16* ABb     = (bf16*)(bufA + 8*1024*1024);        // 8MB at byte-offset 32MB, alive 6..7
    bf16* xnC     = (bf16*)bufC;                        // 33.5MB channel-major xn
    bf16* xnT     = xnC + (size_t)NB*256*LPOS;          // 33.5MB position-major xn
    bf16* f1a     = (bf16*)bufA;                        // step 14: batches 0-7 f1 (64MiB)
    bf16* f1b     = (bf16*)bufC;                        // step 14: batches 8-15 f1 (64MiB)
    bf16* x3t     = (bf16*)bufD;                        // 33.5MB pos-major x3 (bcdt2 dead)
    bf16* fc1_wb  = (bf16*)(bufD + 9000000);            // byte-offset 36MB (past x3t)
    bf16* fc2_wb  = (bf16*)(bufD + 9200000);
    bf16* hob16   = (bf16*)(bufD + 9400000);
    float* stats  = bufD + 10000000;                    // 16*4096*2 fp32 = 512KB
    bf16* wpad    = (bf16*)hzb;                         // 128KB, alive steps 3b..4

    dim3 blk256(256);
    dim3 blkLN(16, 32);

    // 1. conv1(x) -> bufA
    dwconv3x3_k<<<dim3(NB*256), blk256, 0, stream>>>(x, dw1_w, nullptr, bufA, 256);
    // 2. fused: x1 -> bufB (fp32), xn -> xnC bf16 + xnT bf16
    ln_x1xn_k<<<dim3(NB*64), blkLN, 0, stream>>>(bufA, x, bufB, xnC, xnT,
                                                 dw1_ln_w, dw1_ln_b, alpha + 0, ln_w, ln_b);
    // 3b. padded bf16 bcdt weights
    pad_w_k<<<dim3(256), blk256, 0, stream>>>(bcdt_w, wpad);
    // 4. bcdt = bcdt_w @ xn + b -> bufA (192 rows compact, MFMA)
    gemm_nt_mfma<0><<<dim3(32, 2, NB), blk256, 0, stream>>>(
        wpad, xnT, (void*)bufA, bcdt_b, 192, 256, 256, 256, LPOS,
        0, (size_t)LPOS*256, (size_t)192*LPOS);
    // 5. convm(bcdt) -> bufD
    dwconv3x3_k<<<dim3(NB*192), blk256, 0, stream>>>(bufA, dwm_w, dwm_b, bufD, 192);
    // 5b. CmT = transpose(Cm) bf16
    transpose_cm_k<<<dim3(64, NB), blk256, 0, stream>>>(bufD + (size_t)64*LPOS, CmT);
    // 6. AB = softmax(dt+A)*Bm -> ABb bf16
    softmax_ab_k<<<dim3(NB*64), blk256, 0, stream>>>(bufD, ABb, Avec);
    // 6b. zero h region
    hipMemsetAsync(h_out, 0, (size_t)NB*256*64*sizeof(float), stream);
    // 7. h = xn . AB^T (MFMA, split-K 8, atomicAdd) -> 256 blocks = 1/CU
    gemm_h_mfma<<<dim3(8, 2, NB), blk256, 0, stream>>>(xnC, ABb, h_out, 512);
    // 8-10. fused mixer tail: hz -> hg -> ho (bf16 out), one block per batch
    mixer_tail_k<<<dim3(NB), dim3(512), 0, stream>>>(h_out, hz_w, hz_b, outp_w, outp_b, hob16);
    // 10b. bf16 weight converts for FFN
    f2b_k<<<dim3(1024), blk256, 0, stream>>>(fc1_w, fc1_wb, 1024*256);
    f2b_k<<<dim3(1024), blk256, 0, stream>>>(fc2_w, fc2_wb, 256*1024);
    // 11. x2 = (1-a1)x1 + a1*(ho@Cm + xn*Dp) (in-place bufB), MFMA
    mixer_out_mfma<<<dim3(32, 2, NB), blk256, 0, stream>>>(hob16, CmT, xnC, bufB, Dp, alpha + 256);
    // 12. conv2(x2) -> bufA
    dwconv3x3_k<<<dim3(NB*256), blk256, 0, stream>>>(bufB, dw2_w, nullptr, bufA, 256);
    // 13. x3 = (1-a2)x2 + a2*LN(conv2) (in-place bufB) + x3t bf16 pos-major
    ln2d_k<<<dim3(NB*64), blkLN, 0, stream>>>(bufA, bufB, bufB, dw2_ln_w, dw2_ln_b, alpha + 512, x3t, 1);
    // 14. FFN over all 16 batches: 2x fc1+stats (8 batches each into f1a/f1b),
    //     then ONE fc2_out over 16 batches (grid (64,1,16), reg-staged B, 2 barriers/k-step)
    hipMemsetAsync(stats, 0, (size_t)16*LPOS*2*sizeof(float), stream);
    gemm_fc1_stats<<<dim3(8, 32, 8), blk256, 0, stream>>>(x3t, fc1_wb, f1a, stats);
    gemm_fc1_stats<<<dim3(8, 32, 8), blk256, 0, stream>>>(x3t + (size_t)8*LPOS*256, fc1_wb, f1b,
                                                          stats + (size_t)8*LPOS*2);
    gemm_fc2_out<<<dim3(64, 1, 16), dim3(512), 0, stream>>>(
        fc2_wb, f1a, f1b, stats, fc1_ln_w, fc1_ln_b, bufB, outp,
        fc2_ln_w, fc2_ln_b, alpha + 768);
}